// Round 11
// baseline (847.806 us; speedup 1.0000x reference)
//
#include <hip/hip_runtime.h>

using u16 = unsigned short;
typedef __attribute__((ext_vector_type(8))) __bf16 bf16x8;
typedef __attribute__((ext_vector_type(4))) float  f32x4;
typedef __attribute__((ext_vector_type(8))) u16    u16x8;
typedef __attribute__((ext_vector_type(4))) u16    u16x4;

#define NB   4
#define DIM  384
#define NPIX 16384

__device__ __forceinline__ u16 f2bf(float f) {
  return __builtin_bit_cast(u16, (__bf16)f);
}
__device__ __forceinline__ float bf2f(u16 u) {
  return (float)__builtin_bit_cast(__bf16, u);
}
__device__ __forceinline__ void gload16(const void* g, void* l) {
  __builtin_amdgcn_global_load_lds(
      (const __attribute__((address_space(1))) void*)g,
      (__attribute__((address_space(3))) void*)l, 16, 0, 0);
}

// ---- fp32 -> hi/lo bf16 pair ----
__global__ void k_cvt2(const float* __restrict__ s, u16* __restrict__ hi,
                       u16* __restrict__ lo, int n) {
  int i = blockIdx.x * 256 + threadIdx.x;
  if (i < n) {
    float v = s[i];
    u16 h = f2bf(v);
    hi[i] = h;
    lo[i] = f2bf(v - bf2f(h));
  }
}

// ---- transpose+split x: (NB,DIM,NPIX) f32 -> (NB,NPIX,DIM) hi/lo bf16 ----
// 64-channel tiles: each thread stores one FULL 128B line per buffer.
__global__ void k_splitx(const float* __restrict__ x, u16* __restrict__ xhi,
                         u16* __restrict__ xlo) {
  __shared__ float tile[64][33];
  const int tid = threadIdx.x;
  const int n0 = blockIdx.x * 32, c0 = blockIdx.y * 64, b = blockIdx.z;
  const int tj = tid & 31, ti = tid >> 5;
  const float* xp = x + ((size_t)b * DIM + c0) * NPIX + n0;
  #pragma unroll
  for (int i = 0; i < 8; ++i) {
    const int c = i * 8 + ti;
    tile[c][tj] = xp[(size_t)c * NPIX + tj];
  }
  __syncthreads();
  const int px = tid >> 3, sl = tid & 7;
  u16x8 ph, pl;
  #pragma unroll
  for (int e = 0; e < 8; ++e) {
    const float v = tile[sl * 8 + e][px];
    const u16 h = f2bf(v);
    ph[e] = h;
    pl[e] = f2bf(v - bf2f(h));
  }
  const size_t off = ((size_t)b * NPIX + n0 + px) * DIM + c0 + sl * 8;
  *(u16x8*)(xhi + off) = ph;
  *(u16x8*)(xlo + off) = pl;
}

// ---- 1-term MFMA GEMM, 128x128 tile, glds staging, XOR-swizzled LDS ----
// UNCHANGED (control for the R11 gemmP pipeline A/B).
template<int OUTMODE>
__global__ __launch_bounds__(256, 4)
void k_gemmS(const u16* __restrict__ A, const u16* __restrict__ B,
             void* __restrict__ Out, const float* __restrict__ bias,
             int M, int N, int Kd, size_t Astride)
{
  __shared__ u16 lA[128 * 64];
  __shared__ u16 lB[128 * 64];
  const int tid = threadIdx.x, wid = tid >> 6, lane = tid & 63;
  const int GX = gridDim.x, GY = gridDim.y;
  const int W = GX * GY * (int)gridDim.z;
  const int w = blockIdx.x + GX * (blockIdx.y + GY * blockIdx.z);
  const int nw = (w & 7) * (W >> 3) + (w >> 3);
  const int mt = nw % GY;
  const int rest = nw / GY;
  const int ntile = rest % GX;
  const int b = rest / GX;
  const int m0 = mt * 128, n0 = ntile * 128;

  const int srow = lane >> 3;
  const int sslot = (lane & 7) ^ srow;
  const size_t rowA = (size_t)(m0 + wid * 32 + srow) * Kd + sslot * 8 +
                      (size_t)b * Astride;
  const size_t rowB = ((size_t)b * N + n0 + wid * 32 + srow) * Kd + sslot * 8;
  u16* lAw = &lA[(wid * 32) * 64];
  u16* lBw = &lB[(wid * 32) * 64];
  const int wm = (wid & 1) * 64, wn = (wid >> 1) * 64;
  const int cl = lane & 15, rl = lane >> 4;
  const int sxa = cl & 7;

  f32x4 acc[4][4];
  const f32x4 fz = {0.f, 0.f, 0.f, 0.f};
  #pragma unroll
  for (int i = 0; i < 4; ++i)
    #pragma unroll
    for (int j = 0; j < 4; ++j) acc[i][j] = fz;

  const int nk = Kd >> 6;
  for (int kt = 0; kt < nk; ++kt) {
    const u16* Ap = A + rowA + kt * 64;
    const u16* Bp = B + rowB + kt * 64;
    __syncthreads();
    #pragma unroll
    for (int i = 0; i < 4; ++i) {
      gload16(Ap + (size_t)(i * 8) * Kd, lAw + i * 8 * 64);
      gload16(Bp + (size_t)(i * 8) * Kd, lBw + i * 8 * 64);
    }
    __syncthreads();
    #pragma unroll
    for (int ks = 0; ks < 2; ++ks) {
      bf16x8 av[4], bv[4];
      #pragma unroll
      for (int i = 0; i < 4; ++i) {
        av[i] = *(const bf16x8*)&lA[(wm + i * 16 + cl) * 64 + ((ks * 4 + rl) ^ sxa) * 8];
        bv[i] = *(const bf16x8*)&lB[(wn + i * 16 + cl) * 64 + ((ks * 4 + rl) ^ sxa) * 8];
      }
      #pragma unroll
      for (int i = 0; i < 4; ++i)
        #pragma unroll
        for (int j = 0; j < 4; ++j)
          acc[i][j] = __builtin_amdgcn_mfma_f32_16x16x32_bf16(av[i], bv[j], acc[i][j], 0, 0, 0);
    }
  }

  #pragma unroll
  for (int i = 0; i < 4; ++i) {
    #pragma unroll
    for (int j = 0; j < 4; ++j) {
      #pragma unroll
      for (int r = 0; r < 4; ++r) {
        const int m = m0 + wm + i * 16 + rl * 4 + r;
        const int n = n0 + wn + j * 16 + cl;
        const float v = acc[i][j][r] + bias[m];
        const size_t o = ((size_t)b * M + m) * N + n;
        if (OUTMODE == 0) ((float*)Out)[o] = v;
        else ((u16*)Out)[o] = f2bf(v);
      }
    }
  }
}

// ---- 3-term packed MFMA GEMM, R11: double-buffered LDS + counted vmcnt ----
// T4 pipeline: raw s_barrier (no implicit vmcnt(0) drain) + asm
// s_waitcnt vmcnt(8) keeps the next chunk's 8 global_load_lds in flight
// across the barrier; they land under the MFMA phase. Safety: per-wave
// vmcnt(8) before barrier => at release ALL waves' chunk-kt loads landed;
// post-MFMA barrier => all ds_reads of the restage target retired (stage
// writes the OTHER buffer than next iteration's compute). LDS 64KB ->
// 2 blocks/CU. gemmS left unchanged as within-run control.
template<int OUTMODE, bool SSQ>
__global__ __launch_bounds__(256, 2)
void k_gemmP(const u16* __restrict__ Ahi, const u16* __restrict__ Alo,
             const u16* __restrict__ Bhi, const u16* __restrict__ Blo,
             void* __restrict__ Out, u16* __restrict__ OutLo,
             const float* __restrict__ bias, float* __restrict__ ssq,
             int M, int N, int Kd)
{
  __shared__ u16 lA[2][128 * 64];
  __shared__ u16 lB[2][128 * 64];
  const int tid = threadIdx.x, wid = tid >> 6, lane = tid & 63;
  const int GX = gridDim.x, GY = gridDim.y;
  const int W = GX * GY * (int)gridDim.z;
  const int w = blockIdx.x + GX * (blockIdx.y + GY * blockIdx.z);
  const int nw = (w & 7) * (W >> 3) + (w >> 3);
  const int mt = nw % GY;
  const int rest = nw / GY;
  const int ntile = rest % GX;
  const int b = rest / GX;
  const int m0 = mt * 128, n0 = ntile * 128;

  const int srow = lane >> 3;
  const int sp = (lane & 7) ^ srow;
  const int scol = (sp & 3) * 8;
  const u16* baseA = (sp < 4) ? Ahi : Alo;
  const u16* baseB = (sp < 4) ? Bhi : Blo;
  const u16* srcA[4];
  const u16* srcB[4];
  #pragma unroll
  for (int i = 0; i < 4; ++i) {
    srcA[i] = baseA + (size_t)(m0 + wid * 32 + i * 8 + srow) * Kd + scol;
    srcB[i] = baseB + ((size_t)b * N + n0 + wid * 32 + i * 8 + srow) * Kd + scol;
  }
  const int woff = (wid * 32) * 64;
  const int wm = (wid & 1) * 64, wn = (wid >> 1) * 64;
  const int cl = lane & 15, rl = lane >> 4;
  const int ph = rl ^ (cl & 7);

  f32x4 acc[4][4];
  const f32x4 fz = {0.f, 0.f, 0.f, 0.f};
  #pragma unroll
  for (int i = 0; i < 4; ++i)
    #pragma unroll
    for (int j = 0; j < 4; ++j) acc[i][j] = fz;

  const int nk = Kd >> 5;

  // prologue: stage chunks 0 and 1 (16 loads in flight)
  #pragma unroll
  for (int i = 0; i < 4; ++i) {
    gload16(srcA[i], &lA[0][woff + i * 8 * 64]);
    gload16(srcB[i], &lB[0][woff + i * 8 * 64]);
  }
  #pragma unroll
  for (int i = 0; i < 4; ++i) {
    gload16(srcA[i] + 32, &lA[1][woff + i * 8 * 64]);
    gload16(srcB[i] + 32, &lB[1][woff + i * 8 * 64]);
  }

  for (int kt = 0; kt < nk; ++kt) {
    if (kt + 1 < nk) {
      asm volatile("s_waitcnt vmcnt(8)" ::: "memory");
    } else {
      asm volatile("s_waitcnt vmcnt(0)" ::: "memory");
    }
    __builtin_amdgcn_s_barrier();
    __builtin_amdgcn_sched_barrier(0);
    const u16* bA = lA[kt & 1];
    const u16* bB = lB[kt & 1];
    bf16x8 avh[4], bvh[4], avl[4], bvl[4];
    #pragma unroll
    for (int i = 0; i < 4; ++i) {
      avh[i] = *(const bf16x8*)&bA[(wm + i * 16 + cl) * 64 + ph * 8];
      bvh[i] = *(const bf16x8*)&bB[(wn + i * 16 + cl) * 64 + ph * 8];
    }
    #pragma unroll
    for (int i = 0; i < 4; ++i)
      #pragma unroll
      for (int j = 0; j < 4; ++j)
        acc[i][j] = __builtin_amdgcn_mfma_f32_16x16x32_bf16(avh[i], bvh[j], acc[i][j], 0, 0, 0);
    #pragma unroll
    for (int i = 0; i < 4; ++i)
      avl[i] = *(const bf16x8*)&bA[(wm + i * 16 + cl) * 64 + (ph ^ 4) * 8];
    #pragma unroll
    for (int i = 0; i < 4; ++i)
      #pragma unroll
      for (int j = 0; j < 4; ++j)
        acc[i][j] = __builtin_amdgcn_mfma_f32_16x16x32_bf16(avl[i], bvh[j], acc[i][j], 0, 0, 0);
    #pragma unroll
    for (int i = 0; i < 4; ++i)
      bvl[i] = *(const bf16x8*)&bB[(wn + i * 16 + cl) * 64 + (ph ^ 4) * 8];
    #pragma unroll
    for (int i = 0; i < 4; ++i)
      #pragma unroll
      for (int j = 0; j < 4; ++j)
        acc[i][j] = __builtin_amdgcn_mfma_f32_16x16x32_bf16(avh[i], bvl[j], acc[i][j], 0, 0, 0);
    __builtin_amdgcn_s_barrier();
    __builtin_amdgcn_sched_barrier(0);
    if (kt + 2 < nk) {
      const int kb = kt & 1;
      #pragma unroll
      for (int i = 0; i < 4; ++i) {
        gload16(srcA[i] + (kt + 2) * 32, &lA[kb][woff + i * 8 * 64]);
        gload16(srcB[i] + (kt + 2) * 32, &lB[kb][woff + i * 8 * 64]);
      }
    }
  }

  float sq[4][4];
  if (SSQ) {
    #pragma unroll
    for (int i = 0; i < 4; ++i)
      #pragma unroll
      for (int r = 0; r < 4; ++r) sq[i][r] = 0.f;
  }
  #pragma unroll
  for (int i = 0; i < 4; ++i) {
    #pragma unroll
    for (int j = 0; j < 4; ++j) {
      #pragma unroll
      for (int r = 0; r < 4; ++r) {
        const int m = m0 + wm + i * 16 + rl * 4 + r;
        const int n = n0 + wn + j * 16 + cl;
        const float v = acc[i][j][r] + bias[m];
        if (SSQ) sq[i][r] += v * v;
        const size_t o = ((size_t)b * M + m) * N + n;
        if (OUTMODE == 0) ((float*)Out)[o] = v;
        else {
          u16 h = f2bf(v);
          ((u16*)Out)[o] = h;
          OutLo[o] = f2bf(v - bf2f(h));
        }
      }
    }
  }
  if (SSQ) {
    #pragma unroll
    for (int i = 0; i < 4; ++i) {
      #pragma unroll
      for (int r = 0; r < 4; ++r) {
        float s = sq[i][r];
        s += __shfl_xor(s, 1);
        s += __shfl_xor(s, 2);
        s += __shfl_xor(s, 4);
        s += __shfl_xor(s, 8);
        if (cl == 0)
          atomicAdd(&ssq[(size_t)b * M + m0 + wm + i * 16 + rl * 4 + r], s);
      }
    }
  }
}

// ---- stencil row helpers: halo via cross-lane shuffle ----
__device__ __forceinline__ void row_acc_f32(const float* __restrict__ rowp,
    int x0, float w0, float w1, float w2,
    float& o0, float& o1, float& o2, float& o3)
{
  float4 r = *(const float4*)(rowp + x0);
  float lm = __shfl_up(r.w, 1);   if (x0 == 0)   lm = 0.f;
  float rt = __shfl_down(r.x, 1); if (x0 == 124) rt = 0.f;
  o0 = fmaf(lm,  w0, fmaf(r.x, w1, fmaf(r.y, w2, o0)));
  o1 = fmaf(r.x, w0, fmaf(r.y, w1, fmaf(r.z, w2, o1)));
  o2 = fmaf(r.y, w0, fmaf(r.z, w1, fmaf(r.w, w2, o2)));
  o3 = fmaf(r.z, w0, fmaf(r.w, w1, fmaf(rt,  w2, o3)));
}
__device__ __forceinline__ void row_acc_bf16(const u16* __restrict__ rowp,
    int x0, float w0, float w1, float w2,
    float& o0, float& o1, float& o2, float& o3)
{
  u16x4 rv = *(const u16x4*)(rowp + x0);
  float r0 = bf2f(rv[0]), r1 = bf2f(rv[1]), r2 = bf2f(rv[2]), r3 = bf2f(rv[3]);
  float lm = __shfl_up(r3, 1);   if (x0 == 0)   lm = 0.f;
  float rt = __shfl_down(r0, 1); if (x0 == 124) rt = 0.f;
  o0 = fmaf(lm, w0, fmaf(r0, w1, fmaf(r1, w2, o0)));
  o1 = fmaf(r0, w0, fmaf(r1, w1, fmaf(r2, w2, o1)));
  o2 = fmaf(r1, w0, fmaf(r2, w1, fmaf(r3, w2, o2)));
  o3 = fmaf(r2, w0, fmaf(r3, w1, fmaf(rt, w2, o3)));
}

// ---- depthwise 3x3 on q,k pre (fp32 in), 4 px/thread, 8 ch/block ----
__global__ __launch_bounds__(256, 4)
void k_dw3qk(const float* __restrict__ src, const float* __restrict__ w9,
             const float* __restrict__ bias, float* __restrict__ qdwbuf,
             u16* __restrict__ khi, u16* __restrict__ klo,
             float* __restrict__ ssqk)
{
  const int tid = threadIdx.x, wv = tid >> 6, lane = tid & 63;
  const int whw = blockIdx.x + 16 * (blockIdx.y + 96 * blockIdx.z);
  const int g = (whw & 7) + 8 * (whw >> 7);
  const int xchunk = (whw >> 3) & 15;
  const int cg = g % 96, b = g / 96;
  const int n0 = xchunk * 1024 + tid * 4;
  const int h = n0 >> 7, x0 = n0 & 127;
  const int c0 = cg * 8;
  const int hm = (h > 0) ? h - 1 : 0, hp = (h < 127) ? h + 1 : 127;
  const float topf = (h > 0) ? 1.f : 0.f, botf = (h < 127) ? 1.f : 0.f;
  const float* base = src + ((size_t)b * 768 + c0) * NPIX;
  const bool isk = (c0 >= 384);
  float ssl[8];
  #pragma unroll
  for (int s = 0; s < 8; ++s) {
    const int c = c0 + s;
    const float* sp = base + (size_t)s * NPIX;
    const float* wc = w9 + c * 9;
    const float bz = bias[c];
    float o0 = bz, o1 = bz, o2 = bz, o3 = bz;
    row_acc_f32(sp + hm * 128, x0, wc[0] * topf, wc[1] * topf, wc[2] * topf, o0, o1, o2, o3);
    row_acc_f32(sp + h  * 128, x0, wc[3], wc[4], wc[5], o0, o1, o2, o3);
    row_acc_f32(sp + hp * 128, x0, wc[6] * botf, wc[7] * botf, wc[8] * botf, o0, o1, o2, o3);
    if (!isk) {
      float4 ov = make_float4(o0, o1, o2, o3);
      *(float4*)(qdwbuf + ((size_t)b * 384 + c) * NPIX + n0) = ov;
      ssl[s] = 0.f;
    } else {
      ssl[s] = o0 * o0 + o1 * o1 + o2 * o2 + o3 * o3;
      u16x4 ph, pl;
      float oo[4] = {o0, o1, o2, o3};
      #pragma unroll
      for (int j = 0; j < 4; ++j) {
        u16 hv = f2bf(oo[j]);
        ph[j] = hv;
        pl[j] = f2bf(oo[j] - bf2f(hv));
      }
      const size_t off = ((size_t)b * 384 + (c - 384)) * NPIX + n0;
      *(u16x4*)(khi + off) = ph;
      *(u16x4*)(klo + off) = pl;
    }
  }
  if (isk) {
    __shared__ float sred[4][8];
    #pragma unroll
    for (int s = 0; s < 8; ++s) {
      float v = ssl[s];
      #pragma unroll
      for (int off = 32; off; off >>= 1) v += __shfl_down(v, off);
      if (lane == 0) sred[wv][s] = v;
    }
    __syncthreads();
    if (tid < 8) {
      float t = sred[0][tid] + sred[1][tid] + sred[2][tid] + sred[3][tid];
      atomicAdd(&ssqk[(size_t)b * DIM + (c0 - 384) + tid], t);
    }
  }
}

// ---- depthwise 3x3 on v pre + TRANSPOSED bf16 out [b][n][384] ----
__global__ __launch_bounds__(512, 4)
void k_dw3vT(const u16* __restrict__ src, const float* __restrict__ w9,
             const float* __restrict__ bias, u16* __restrict__ vT)
{
  __shared__ u16 th[256 * 64];   // 32 KB
  const int tid = threadIdx.x, wv = tid >> 6, lane = tid & 63;
  const int whw = blockIdx.x + 64 * (blockIdx.y + 6 * blockIdx.z);
  const int g = (whw & 7) + 8 * (whw >> 9);
  const int xchunk = (whw >> 3) & 63;
  const int cg = g % 6, b = g / 6;
  const int npx0 = xchunk * 256;
  const int n0 = npx0 + lane * 4;
  const int h = n0 >> 7, x0 = n0 & 127;
  const int c0 = cg * 64 + wv * 8;
  const int hm = (h > 0) ? h - 1 : 0, hp = (h < 127) ? h + 1 : 127;
  const float topf = (h > 0) ? 1.f : 0.f, botf = (h < 127) ? 1.f : 0.f;
  const u16* base = src + ((size_t)b * 384 + c0) * NPIX;
  u16x8 vh[4];
  #pragma unroll
  for (int s = 0; s < 8; ++s) {
    const int c = c0 + s;
    const u16* sp = base + (size_t)s * NPIX;
    const float* wc = w9 + c * 9;
    const float bz = bias[c];
    float o0 = bz, o1 = bz, o2 = bz, o3 = bz;
    row_acc_bf16(sp + hm * 128, x0, wc[0] * topf, wc[1] * topf, wc[2] * topf, o0, o1, o2, o3);
    row_acc_bf16(sp + h  * 128, x0, wc[3], wc[4], wc[5], o0, o1, o2, o3);
    row_acc_bf16(sp + hp * 128, x0, wc[6] * botf, wc[7] * botf, wc[8] * botf, o0, o1, o2, o3);
    vh[0][s] = f2bf(o0); vh[1][s] = f2bf(o1);
    vh[2][s] = f2bf(o2); vh[3][s] = f2bf(o3);
  }
  const int sl = (wv ^ (lane & 7)) * 8;
  #pragma unroll
  for (int j = 0; j < 4; ++j) {
    const int px = lane * 4 + j;
    *(u16x8*)&th[px * 64 + sl] = vh[j];
  }
  __syncthreads();
  if (tid < 256) {
    const int px = tid;
    u16* dst = vT + ((size_t)b * NPIX + npx0 + px) * 384 + cg * 64;
    const int rsw = (px >> 2) & 7;
    #pragma unroll
    for (int s = 0; s < 8; ++s)
      *(u16x8*)(dst + s * 8) = *(const u16x8*)&th[px * 64 + ((s ^ rsw) * 8)];
  }
}

// ---- depthwise 3x3 on [q(fp32), feature(fp32)] + exact GELU ----
__global__ __launch_bounds__(512, 4)
void k_qdw2(const float* __restrict__ qdwbuf, const float* __restrict__ feat,
            const float* __restrict__ w9, const float* __restrict__ bias,
            u16* __restrict__ qfhi, u16* __restrict__ qflo)
{
  __shared__ u16 th[256 * 64];   // 32 KB
  __shared__ u16 tl[256 * 64];   // 32 KB
  const int tid = threadIdx.x, wv = tid >> 6, lane = tid & 63;
  const int whw = blockIdx.x + 64 * (blockIdx.y + 12 * blockIdx.z);
  const int g = (whw & 7) + 8 * (whw >> 9);
  const int xchunk = (whw >> 3) & 63;
  const int cg = g % 12, b = g / 12;
  const int npx0 = xchunk * 256;
  const int n0 = npx0 + lane * 4;
  const int h = n0 >> 7, x0 = n0 & 127;
  const int c0 = cg * 64 + wv * 8;
  const int hm = (h > 0) ? h - 1 : 0, hp = (h < 127) ? h + 1 : 127;
  const float topf = (h > 0) ? 1.f : 0.f, botf = (h < 127) ? 1.f : 0.f;
  const bool isq = (c0 < 384);
  const float* base = isq ? (qdwbuf + ((size_t)b * 384 + c0) * NPIX)
                          : (feat   + ((size_t)b * 384 + (c0 - 384)) * NPIX);
  u16x8 vh[4], vl[4];
  #pragma unroll
  for (int s = 0; s < 8; ++s) {
    const int c = c0 + s;
    const float* sp = base + (size_t)s * NPIX;
    const float* wc = w9 + c * 9;
    const float bz = bias[c];
    float o0 = bz, o1 = bz, o2 = bz, o3 = bz;
    row_acc_f32(sp + hm * 128, x0, wc[0] * topf, wc[1] * topf, wc[2] * topf, o0, o1, o2, o3);
    row_acc_f32(sp + h  * 128, x0, wc[3], wc[4], wc[5], o0, o1, o2, o3);
    row_acc_f32(sp + hp * 128, x0, wc[6] * botf, wc[7] * botf, wc[8] * botf, o0, o1, o2, o3);
    float oo[4] = {o0, o1, o2, o3};
    #pragma unroll
    for (int j = 0; j < 4; ++j) {
      const float a = oo[j];
      const float g2 = 0.5f * a * (1.0f + erff(a * 0.70710678118654752440f));
      const u16 hv = f2bf(g2);
      vh[j][s] = hv;
      vl[j][s] = f2bf(g2 - bf2f(hv));
    }
  }
  const int sl = (wv ^ (lane & 7)) * 8;
  #pragma unroll
  for (int j = 0; j < 4; ++j) {
    const int px = lane * 4 + j;
    *(u16x8*)&th[px * 64 + sl] = vh[j];
    *(u16x8*)&tl[px * 64 + sl] = vl[j];
  }
  __syncthreads();
  const int sel = tid >> 8;
  const int px = tid & 255;
  const u16* srcb = sel ? tl : th;
  u16* dst = (sel ? qflo : qfhi) +
             ((size_t)b * NPIX + npx0 + px) * 768 + cg * 64;
  const int rsw = (px >> 2) & 7;
  #pragma unroll
  for (int s = 0; s < 8; ++s)
    *(u16x8*)(dst + s * 8) = *(const u16x8*)&srcb[px * 64 + ((s ^ rsw) * 8)];
}

// ---- QK^T 3-term: 2 chunks/block, 64 wave partials per bh ----
__global__ __launch_bounds__(256)
void k_qk3(const u16* __restrict__ qhi, const u16* __restrict__ qlo,
           const u16* __restrict__ khi, const u16* __restrict__ klo,
           float* __restrict__ part)
{
  const int wid = threadIdx.x >> 6, lane = threadIdx.x & 63;
  const int bh = blockIdx.y;
  const int b = bh >> 3, hd = bh & 7;
  const size_t base = ((size_t)b * 384 + hd * 48) * NPIX;
  const int cl = lane & 15, rl = lane >> 4;
  f32x4 acc[3][3];
  const f32x4 fz = {0.f, 0.f, 0.f, 0.f};
  #pragma unroll
  for (int i = 0; i < 3; ++i)
    #pragma unroll
    for (int j = 0; j < 3; ++j) acc[i][j] = fz;
  for (int ck = 0; ck < 2; ++ck) {
    const int n0 = (blockIdx.x * 2 + ck) * 512 + wid * 128;
    #pragma unroll
    for (int ks = 0; ks < 4; ++ks) {
      const int nn = n0 + ks * 32 + rl * 8;
      bf16x8 ah[3], al[3], bh16[3], bl16[3];
      #pragma unroll
      for (int i = 0; i < 3; ++i) {
        const size_t ro = base + (size_t)(i * 16 + cl) * NPIX + nn;
        ah[i]   = *(const bf16x8*)&qhi[ro];
        al[i]   = *(const bf16x8*)&qlo[ro];
        bh16[i] = *(const bf16x8*)&khi[ro];
        bl16[i] = *(const bf16x8*)&klo[ro];
      }
      #pragma unroll
      for (int i = 0; i < 3; ++i)
        #pragma unroll
        for (int j = 0; j < 3; ++j) {
          acc[i][j] = __builtin_amdgcn_mfma_f32_16x16x32_bf16(ah[i], bh16[j], acc[i][j], 0, 0, 0);
          acc[i][j] = __builtin_amdgcn_mfma_f32_16x16x32_bf16(ah[i], bl16[j], acc[i][j], 0, 0, 0);
          acc[i][j] = __builtin_amdgcn_mfma_f32_16x16x32_bf16(al[i], bh16[j], acc[i][j], 0, 0, 0);
        }
    }
  }
  float* pp = part + ((size_t)bh * 64 + blockIdx.x * 4 + wid) * 2304;
  #pragma unroll
  for (int i = 0; i < 3; ++i)
    #pragma unroll
    for (int j = 0; j < 3; ++j)
      #pragma unroll
      for (int r = 0; r < 4; ++r)
        pp[(i * 16 + rl * 4 + r) * 48 + (j * 16 + cl)] = acc[i][j][r];
}

// ---- reduce 64 partials -> raw[bh][48][48]  (288 blocks: TLP-bound) ----
__global__ void k_qkred(const float* __restrict__ part, float* __restrict__ raw)
{
  const int bh = blockIdx.x;
  const int p = blockIdx.y * 256 + threadIdx.x;   // < 2304
  const float* pp = part + (size_t)bh * 64 * 2304 + p;
  float s = 0.f;
  #pragma unroll 8
  for (int w = 0; w < 64; ++w) s += pp[(size_t)w * 2304];
  raw[(size_t)bh * 2304 + p] = s;
}

// ---- fused topk+softmax+Wa, WAVE-PARALLEL topk ----
__global__ void k_attn2(const float* __restrict__ raw, const float* __restrict__ ssq_q,
                        const float* __restrict__ ssq_k, const float* __restrict__ temp,
                        const int* __restrict__ Kp, const float* __restrict__ W,
                        u16* __restrict__ WaHi)
{
  __shared__ float at[48 * 49];
  const int bh = blockIdx.x, b = bh >> 3, hd = bh & 7;
  const int tid = threadIdx.x, wv = tid >> 6, lane = tid & 63;
  const int K = *Kp;
  const int d = lane;
  const bool act = (d < 48);
  const float ki = act ? 1.0f / fmaxf(sqrtf(ssq_k[b * DIM + hd * 48 + d]), 1e-12f) : 0.f;
  const float tmp = temp[hd];
  for (int r = 0; r < 12; ++r) {
    const int c = wv * 12 + r;
    const float qi = tmp / fmaxf(sqrtf(ssq_q[b * DIM + hd * 48 + c]), 1e-12f);
    const float v = act ? raw[(size_t)bh * 2304 + c * 48 + d] * qi * ki : -3.0e38f;
    int rank = 0;
    #pragma unroll
    for (int e = 0; e < 48; ++e) {
      const float ve = __shfl(v, e);
      rank += (ve > v || (ve == v && e < d)) ? 1 : 0;
    }
    const bool keep = act && (rank < K);
    float mx = keep ? v : -3.0e38f;
    #pragma unroll
    for (int off = 32; off; off >>= 1) mx = fmaxf(mx, __shfl_xor(mx, off));
    const float ex = keep ? expf(v - mx) : 0.f;
    float sum = ex;
    #pragma unroll
    for (int off = 32; off; off >>= 1) sum += __shfl_xor(sum, off);
    const float rs = 1.0f / sum;
    if (act) at[c * 49 + d] = ex * rs;
  }
  __syncthreads();
  for (int idx = tid; idx < 384 * 48; idx += 256) {
    const int m = idx / 48, dd = idx - m * 48;
    const float* wr = W + (size_t)m * 384 + hd * 48;
    float s = 0.f;
    #pragma unroll
    for (int c = 0; c < 48; ++c) s += wr[c] * at[c * 49 + dd];
    WaHi[((size_t)b * 384 + m) * 384 + hd * 48 + dd] = f2bf(s);
  }
}

extern "C" void kernel_launch(void* const* d_in, const int* in_sizes, int n_in,
                              void* d_out, int out_size, void* d_ws, size_t ws_size,
                              hipStream_t stream)
{
  (void)in_sizes; (void)n_in; (void)out_size; (void)ws_size;
  const float* x      = (const float*)d_in[0];
  const float* feat   = (const float*)d_in[1];
  const float* qkv_w  = (const float*)d_in[2];
  const float* qkv_b  = (const float*)d_in[3];
  const float* dw_w   = (const float*)d_in[4];
  const float* dw_b   = (const float*)d_in[5];
  const float* qdw_w  = (const float*)d_in[6];
  const float* qdw_b  = (const float*)d_in[7];
  const float* qpw_w  = (const float*)d_in[8];
  const float* qpw_b  = (const float*)d_in[9];
  const float* proj_w = (const float*)d_in[10];
  const float* proj_b = (const float*)d_in[11];
  const float* temp   = (const float*)d_in[12];
  const int*   Kp     = (const int*)d_in[13];

  char* ws = (char*)d_ws;
  const size_t HALF = 50331648;   // 48 MiB = NB*NPIX*DIM*2 bytes

  // R0 [0,16Mi): weights + attention small buffers
  u16* WqkvHi = (u16*)ws;                          // 1152*384
  u16* WqkvLo = WqkvHi + 1152 * 384;
  u16* WqpwHi = WqkvLo + 1152 * 384;               // 384*768
  u16* WqpwLo = WqpwHi + 384 * 768;
  float* ssqQ = (float*)(ws + 3244032);            // NB*DIM
  float* ssqK = ssqQ + NB * DIM;                   // NB*DIM
  float* raw  = ssqK + NB * DIM;                   // 32*2304 f32
  u16* WaHi   = (u16*)(ws + (4ull << 20));         // NB*384*384
  // R1 [16Mi, 112Mi): xThi/xTlo -> q_dw fp32 -> qhi/qlo
  char* R1 = ws + (16ull << 20);
  u16* xThi = (u16*)R1;
  u16* xTlo = (u16*)(R1 + HALF);
  float* qdwbuf = (float*)R1;                      // 96 MiB
  u16* qHi = (u16*)R1;
  u16* qLo = (u16*)(R1 + HALF);
  // R2 [112Mi, 304Mi): qk_pre fp32 -> qfT hi/lo -> (part 18.9MB -> vT)
  char* R2 = ws + (112ull << 20);
  float* qkpre = (float*)R2;                       // 192 MiB
  u16* qfHi = (u16*)R2;
  u16* qfLo = (u16*)(R2 + 2 * HALF);
  float* part = (float*)R2;                        // 32*64*2304 f32 (18.9 MiB)
  u16* vT   = (u16*)R2;                            // after k_qkred, 48 MiB
  // R3 [304Mi, 352Mi): v_pre bf16
  u16* vpre = (u16*)(ws + (304ull << 20));
  // d_out: khi/klo until proj overwrites
  u16* kHi = (u16*)d_out;
  u16* kLo = kHi + (size_t)NB * DIM * NPIX;

  hipMemsetAsync(ssqQ, 0, 2 * NB * DIM * sizeof(float), stream);
  k_cvt2<<<dim3(1728), 256, 0, stream>>>(qkv_w, WqkvHi, WqkvLo, 1152 * 384);
  k_cvt2<<<dim3(1152), 256, 0, stream>>>(qpw_w, WqpwHi, WqpwLo, 384 * 768);
  k_splitx<<<dim3(512, 6, NB), 256, 0, stream>>>(x, xThi, xTlo);
  // qkv GEMM, q+k channels, packed 3-term, fp32 out
  k_gemmP<0, false><<<dim3(128, 6, NB), 256, 0, stream>>>(WqkvHi, WqkvLo, xThi, xTlo,
      (void*)qkpre, nullptr, qkv_b, nullptr, 768, NPIX, 384);
  // qkv GEMM, v channels, 1-term, bf16 out
  k_gemmS<1><<<dim3(128, 3, NB), 256, 0, stream>>>(WqkvHi + (size_t)768 * 384,
      xThi, (void*)vpre, qkv_b + 768, 384, NPIX, 384, 0);
  k_dw3qk<<<dim3(16, 96, NB), 256, 0, stream>>>(qkpre, dw_w, dw_b, qdwbuf, kHi, kLo, ssqK);
  k_qdw2<<<dim3(64, 12, NB), 512, 0, stream>>>(qdwbuf, feat, qdw_w, qdw_b, qfHi, qfLo);
  // qpw GEMM, packed 3-term, hi/lo out, fused q sum-of-squares
  k_gemmP<2, true><<<dim3(128, 3, NB), 256, 0, stream>>>(WqpwHi, WqpwLo, qfHi, qfLo,
      (void*)qHi, qLo, qpw_b, ssqQ, 384, NPIX, 768);
  k_qk3<<<dim3(16, 32), 256, 0, stream>>>(qHi, qLo, kHi, kLo, part);
  k_qkred<<<dim3(32, 9), 256, 0, stream>>>(part, raw);
  // fused topk/softmax + Wa = Wproj*attn (wave-parallel topk)
  k_attn2<<<dim3(32), 256, 0, stream>>>(raw, ssqQ, ssqK, temp, Kp, proj_w, WaHi);
  // v depthwise (transposed out) AFTER k_qkred so vT can reuse R2
  k_dw3vT<<<dim3(64, 6, NB), 512, 0, stream>>>(vpre, dw_w + 768 * 9, dw_b + 768, vT);
  // fused proj: out = (Wproj*attn) * V, per-batch A
  k_gemmS<0><<<dim3(128, 3, NB), 256, 0, stream>>>(WaHi, vT,
      d_out, proj_b, 384, NPIX, 384, (size_t)384 * 384);
}

// Round 12
// 810.349 us; speedup vs baseline: 1.0462x; 1.0462x over previous
//
#include <hip/hip_runtime.h>

using u16 = unsigned short;
typedef __attribute__((ext_vector_type(8))) __bf16 bf16x8;
typedef __attribute__((ext_vector_type(4))) float  f32x4;
typedef __attribute__((ext_vector_type(8))) u16    u16x8;
typedef __attribute__((ext_vector_type(4))) u16    u16x4;

#define NB   4
#define DIM  384
#define NPIX 16384

__device__ __forceinline__ u16 f2bf(float f) {
  return __builtin_bit_cast(u16, (__bf16)f);
}
__device__ __forceinline__ float bf2f(u16 u) {
  return (float)__builtin_bit_cast(__bf16, u);
}
__device__ __forceinline__ void gload16(const void* g, void* l) {
  __builtin_amdgcn_global_load_lds(
      (const __attribute__((address_space(1))) void*)g,
      (__attribute__((address_space(3))) void*)l, 16, 0, 0);
}

// ---- fp32 -> hi/lo bf16 pair, two sources in one launch ----
__global__ void k_cvt2x(const float* __restrict__ s0, u16* __restrict__ hi0,
                        u16* __restrict__ lo0, int n0,
                        const float* __restrict__ s1, u16* __restrict__ hi1,
                        u16* __restrict__ lo1, int n1) {
  int i = blockIdx.x * 256 + threadIdx.x;
  const float* s; u16* hi; u16* lo; int n;
  if (blockIdx.y == 0) { s = s0; hi = hi0; lo = lo0; n = n0; }
  else                 { s = s1; hi = hi1; lo = lo1; n = n1; }
  if (i < n) {
    float v = s[i];
    u16 h = f2bf(v);
    hi[i] = h;
    lo[i] = f2bf(v - bf2f(h));
  }
}

// ---- transpose+split x: (NB,DIM,NPIX) f32 -> (NB,NPIX,DIM) hi/lo bf16 ----
// 64-channel tiles: each thread stores one FULL 128B line per buffer.
__global__ void k_splitx(const float* __restrict__ x, u16* __restrict__ xhi,
                         u16* __restrict__ xlo) {
  __shared__ float tile[64][33];
  const int tid = threadIdx.x;
  const int n0 = blockIdx.x * 32, c0 = blockIdx.y * 64, b = blockIdx.z;
  const int tj = tid & 31, ti = tid >> 5;
  const float* xp = x + ((size_t)b * DIM + c0) * NPIX + n0;
  #pragma unroll
  for (int i = 0; i < 8; ++i) {
    const int c = i * 8 + ti;
    tile[c][tj] = xp[(size_t)c * NPIX + tj];
  }
  __syncthreads();
  const int px = tid >> 3, sl = tid & 7;
  u16x8 ph, pl;
  #pragma unroll
  for (int e = 0; e < 8; ++e) {
    const float v = tile[sl * 8 + e][px];
    const u16 h = f2bf(v);
    ph[e] = h;
    pl[e] = f2bf(v - bf2f(h));
  }
  const size_t off = ((size_t)b * NPIX + n0 + px) * DIM + c0 + sl * 8;
  *(u16x8*)(xhi + off) = ph;
  *(u16x8*)(xlo + off) = pl;
}

// ---- 1-term MFMA GEMM, 128x128 tile, glds staging, XOR-swizzled LDS ----
// (256,4): proven config. Astride: per-batch A offset (elements); 0 = shared A.
template<int OUTMODE>
__global__ __launch_bounds__(256, 4)
void k_gemmS(const u16* __restrict__ A, const u16* __restrict__ B,
             void* __restrict__ Out, const float* __restrict__ bias,
             int M, int N, int Kd, size_t Astride)
{
  __shared__ u16 lA[128 * 64];
  __shared__ u16 lB[128 * 64];
  const int tid = threadIdx.x, wid = tid >> 6, lane = tid & 63;
  const int GX = gridDim.x, GY = gridDim.y;
  const int W = GX * GY * (int)gridDim.z;
  const int w = blockIdx.x + GX * (blockIdx.y + GY * blockIdx.z);
  const int nw = (w & 7) * (W >> 3) + (w >> 3);
  const int mt = nw % GY;
  const int rest = nw / GY;
  const int ntile = rest % GX;
  const int b = rest / GX;
  const int m0 = mt * 128, n0 = ntile * 128;

  const int srow = lane >> 3;
  const int sslot = (lane & 7) ^ srow;
  const size_t rowA = (size_t)(m0 + wid * 32 + srow) * Kd + sslot * 8 +
                      (size_t)b * Astride;
  const size_t rowB = ((size_t)b * N + n0 + wid * 32 + srow) * Kd + sslot * 8;
  u16* lAw = &lA[(wid * 32) * 64];
  u16* lBw = &lB[(wid * 32) * 64];
  const int wm = (wid & 1) * 64, wn = (wid >> 1) * 64;
  const int cl = lane & 15, rl = lane >> 4;
  const int sxa = cl & 7;

  f32x4 acc[4][4];
  const f32x4 fz = {0.f, 0.f, 0.f, 0.f};
  #pragma unroll
  for (int i = 0; i < 4; ++i)
    #pragma unroll
    for (int j = 0; j < 4; ++j) acc[i][j] = fz;

  const int nk = Kd >> 6;
  for (int kt = 0; kt < nk; ++kt) {
    const u16* Ap = A + rowA + kt * 64;
    const u16* Bp = B + rowB + kt * 64;
    __syncthreads();
    #pragma unroll
    for (int i = 0; i < 4; ++i) {
      gload16(Ap + (size_t)(i * 8) * Kd, lAw + i * 8 * 64);
      gload16(Bp + (size_t)(i * 8) * Kd, lBw + i * 8 * 64);
    }
    __syncthreads();
    #pragma unroll
    for (int ks = 0; ks < 2; ++ks) {
      bf16x8 av[4], bv[4];
      #pragma unroll
      for (int i = 0; i < 4; ++i) {
        av[i] = *(const bf16x8*)&lA[(wm + i * 16 + cl) * 64 + ((ks * 4 + rl) ^ sxa) * 8];
        bv[i] = *(const bf16x8*)&lB[(wn + i * 16 + cl) * 64 + ((ks * 4 + rl) ^ sxa) * 8];
      }
      #pragma unroll
      for (int i = 0; i < 4; ++i)
        #pragma unroll
        for (int j = 0; j < 4; ++j)
          acc[i][j] = __builtin_amdgcn_mfma_f32_16x16x32_bf16(av[i], bv[j], acc[i][j], 0, 0, 0);
    }
  }

  #pragma unroll
  for (int i = 0; i < 4; ++i) {
    #pragma unroll
    for (int j = 0; j < 4; ++j) {
      #pragma unroll
      for (int r = 0; r < 4; ++r) {
        const int m = m0 + wm + i * 16 + rl * 4 + r;
        const int n = n0 + wn + j * 16 + cl;
        const float v = acc[i][j][r] + bias[m];
        const size_t o = ((size_t)b * M + m) * N + n;
        if (OUTMODE == 0) ((float*)Out)[o] = v;
        else ((u16*)Out)[o] = f2bf(v);
      }
    }
  }
}

// ---- 3-term packed MFMA GEMM: per 32-K chunk, LDS rows hold [hi32|lo32] ----
// R12: reverted to the proven R10 single-buffer (256,4) form. R11's
// dbuf+counted-vmcnt graft cost occupancy (33->19%) and regressed 160->172us
// (m114: cross-block wave overlap at 4 blocks/CU already hides the drain).
template<int OUTMODE, bool SSQ>
__global__ __launch_bounds__(256, 4)
void k_gemmP(const u16* __restrict__ Ahi, const u16* __restrict__ Alo,
             const u16* __restrict__ Bhi, const u16* __restrict__ Blo,
             void* __restrict__ Out, u16* __restrict__ OutLo,
             const float* __restrict__ bias, float* __restrict__ ssq,
             int M, int N, int Kd)
{
  __shared__ u16 lA[128 * 64];
  __shared__ u16 lB[128 * 64];
  const int tid = threadIdx.x, wid = tid >> 6, lane = tid & 63;
  const int GX = gridDim.x, GY = gridDim.y;
  const int W = GX * GY * (int)gridDim.z;
  const int w = blockIdx.x + GX * (blockIdx.y + GY * blockIdx.z);
  const int nw = (w & 7) * (W >> 3) + (w >> 3);
  const int mt = nw % GY;
  const int rest = nw / GY;
  const int ntile = rest % GX;
  const int b = rest / GX;
  const int m0 = mt * 128, n0 = ntile * 128;

  const int srow = lane >> 3;
  const int sp = (lane & 7) ^ srow;
  const int scol = (sp & 3) * 8;
  const u16* baseA = (sp < 4) ? Ahi : Alo;
  const u16* baseB = (sp < 4) ? Bhi : Blo;
  const u16* srcA[4];
  const u16* srcB[4];
  #pragma unroll
  for (int i = 0; i < 4; ++i) {
    srcA[i] = baseA + (size_t)(m0 + wid * 32 + i * 8 + srow) * Kd + scol;
    srcB[i] = baseB + ((size_t)b * N + n0 + wid * 32 + i * 8 + srow) * Kd + scol;
  }
  u16* lAw = &lA[(wid * 32) * 64];
  u16* lBw = &lB[(wid * 32) * 64];
  const int wm = (wid & 1) * 64, wn = (wid >> 1) * 64;
  const int cl = lane & 15, rl = lane >> 4;
  const int ph = rl ^ (cl & 7);

  f32x4 acc[4][4];
  const f32x4 fz = {0.f, 0.f, 0.f, 0.f};
  #pragma unroll
  for (int i = 0; i < 4; ++i)
    #pragma unroll
    for (int j = 0; j < 4; ++j) acc[i][j] = fz;

  const int nk = Kd >> 5;
  for (int kt = 0; kt < nk; ++kt) {
    __syncthreads();
    #pragma unroll
    for (int i = 0; i < 4; ++i) {
      gload16(srcA[i] + kt * 32, lAw + i * 8 * 64);
      gload16(srcB[i] + kt * 32, lBw + i * 8 * 64);
    }
    __syncthreads();
    bf16x8 avh[4], bvh[4], avl[4], bvl[4];
    #pragma unroll
    for (int i = 0; i < 4; ++i) {
      avh[i] = *(const bf16x8*)&lA[(wm + i * 16 + cl) * 64 + ph * 8];
      bvh[i] = *(const bf16x8*)&lB[(wn + i * 16 + cl) * 64 + ph * 8];
    }
    #pragma unroll
    for (int i = 0; i < 4; ++i)
      #pragma unroll
      for (int j = 0; j < 4; ++j)
        acc[i][j] = __builtin_amdgcn_mfma_f32_16x16x32_bf16(avh[i], bvh[j], acc[i][j], 0, 0, 0);
    #pragma unroll
    for (int i = 0; i < 4; ++i)
      avl[i] = *(const bf16x8*)&lA[(wm + i * 16 + cl) * 64 + (ph ^ 4) * 8];
    #pragma unroll
    for (int i = 0; i < 4; ++i)
      #pragma unroll
      for (int j = 0; j < 4; ++j)
        acc[i][j] = __builtin_amdgcn_mfma_f32_16x16x32_bf16(avl[i], bvh[j], acc[i][j], 0, 0, 0);
    #pragma unroll
    for (int i = 0; i < 4; ++i)
      bvl[i] = *(const bf16x8*)&lB[(wn + i * 16 + cl) * 64 + (ph ^ 4) * 8];
    #pragma unroll
    for (int i = 0; i < 4; ++i)
      #pragma unroll
      for (int j = 0; j < 4; ++j)
        acc[i][j] = __builtin_amdgcn_mfma_f32_16x16x32_bf16(avh[i], bvl[j], acc[i][j], 0, 0, 0);
  }

  float sq[4][4];
  if (SSQ) {
    #pragma unroll
    for (int i = 0; i < 4; ++i)
      #pragma unroll
      for (int r = 0; r < 4; ++r) sq[i][r] = 0.f;
  }
  #pragma unroll
  for (int i = 0; i < 4; ++i) {
    #pragma unroll
    for (int j = 0; j < 4; ++j) {
      #pragma unroll
      for (int r = 0; r < 4; ++r) {
        const int m = m0 + wm + i * 16 + rl * 4 + r;
        const int n = n0 + wn + j * 16 + cl;
        const float v = acc[i][j][r] + bias[m];
        if (SSQ) sq[i][r] += v * v;
        const size_t o = ((size_t)b * M + m) * N + n;
        if (OUTMODE == 0) ((float*)Out)[o] = v;
        else {
          u16 h = f2bf(v);
          ((u16*)Out)[o] = h;
          OutLo[o] = f2bf(v - bf2f(h));
        }
      }
    }
  }
  if (SSQ) {
    #pragma unroll
    for (int i = 0; i < 4; ++i) {
      #pragma unroll
      for (int r = 0; r < 4; ++r) {
        float s = sq[i][r];
        s += __shfl_xor(s, 1);
        s += __shfl_xor(s, 2);
        s += __shfl_xor(s, 4);
        s += __shfl_xor(s, 8);
        if (cl == 0)
          atomicAdd(&ssq[(size_t)b * M + m0 + wm + i * 16 + rl * 4 + r], s);
      }
    }
  }
}

// ---- stencil row helpers: halo via cross-lane shuffle ----
__device__ __forceinline__ void row_acc_f32(const float* __restrict__ rowp,
    int x0, float w0, float w1, float w2,
    float& o0, float& o1, float& o2, float& o3)
{
  float4 r = *(const float4*)(rowp + x0);
  float lm = __shfl_up(r.w, 1);   if (x0 == 0)   lm = 0.f;
  float rt = __shfl_down(r.x, 1); if (x0 == 124) rt = 0.f;
  o0 = fmaf(lm,  w0, fmaf(r.x, w1, fmaf(r.y, w2, o0)));
  o1 = fmaf(r.x, w0, fmaf(r.y, w1, fmaf(r.z, w2, o1)));
  o2 = fmaf(r.y, w0, fmaf(r.z, w1, fmaf(r.w, w2, o2)));
  o3 = fmaf(r.z, w0, fmaf(r.w, w1, fmaf(rt,  w2, o3)));
}
__device__ __forceinline__ void row_acc_bf16(const u16* __restrict__ rowp,
    int x0, float w0, float w1, float w2,
    float& o0, float& o1, float& o2, float& o3)
{
  u16x4 rv = *(const u16x4*)(rowp + x0);
  float r0 = bf2f(rv[0]), r1 = bf2f(rv[1]), r2 = bf2f(rv[2]), r3 = bf2f(rv[3]);
  float lm = __shfl_up(r3, 1);   if (x0 == 0)   lm = 0.f;
  float rt = __shfl_down(r0, 1); if (x0 == 124) rt = 0.f;
  o0 = fmaf(lm, w0, fmaf(r0, w1, fmaf(r1, w2, o0)));
  o1 = fmaf(r0, w0, fmaf(r1, w1, fmaf(r2, w2, o1)));
  o2 = fmaf(r1, w0, fmaf(r2, w1, fmaf(r3, w2, o2)));
  o3 = fmaf(r2, w0, fmaf(r3, w1, fmaf(rt, w2, o3)));
}

// ---- depthwise 3x3 on q,k pre (fp32 in), 4 px/thread, 8 ch/block ----
__global__ __launch_bounds__(256, 4)
void k_dw3qk(const float* __restrict__ src, const float* __restrict__ w9,
             const float* __restrict__ bias, float* __restrict__ qdwbuf,
             u16* __restrict__ khi, u16* __restrict__ klo,
             float* __restrict__ ssqk)
{
  const int tid = threadIdx.x, wv = tid >> 6, lane = tid & 63;
  const int whw = blockIdx.x + 16 * (blockIdx.y + 96 * blockIdx.z);
  const int g = (whw & 7) + 8 * (whw >> 7);
  const int xchunk = (whw >> 3) & 15;
  const int cg = g % 96, b = g / 96;
  const int n0 = xchunk * 1024 + tid * 4;
  const int h = n0 >> 7, x0 = n0 & 127;
  const int c0 = cg * 8;
  const int hm = (h > 0) ? h - 1 : 0, hp = (h < 127) ? h + 1 : 127;
  const float topf = (h > 0) ? 1.f : 0.f, botf = (h < 127) ? 1.f : 0.f;
  const float* base = src + ((size_t)b * 768 + c0) * NPIX;
  const bool isk = (c0 >= 384);
  float ssl[8];
  #pragma unroll
  for (int s = 0; s < 8; ++s) {
    const int c = c0 + s;
    const float* sp = base + (size_t)s * NPIX;
    const float* wc = w9 + c * 9;
    const float bz = bias[c];
    float o0 = bz, o1 = bz, o2 = bz, o3 = bz;
    row_acc_f32(sp + hm * 128, x0, wc[0] * topf, wc[1] * topf, wc[2] * topf, o0, o1, o2, o3);
    row_acc_f32(sp + h  * 128, x0, wc[3], wc[4], wc[5], o0, o1, o2, o3);
    row_acc_f32(sp + hp * 128, x0, wc[6] * botf, wc[7] * botf, wc[8] * botf, o0, o1, o2, o3);
    if (!isk) {
      float4 ov = make_float4(o0, o1, o2, o3);
      *(float4*)(qdwbuf + ((size_t)b * 384 + c) * NPIX + n0) = ov;
      ssl[s] = 0.f;
    } else {
      ssl[s] = o0 * o0 + o1 * o1 + o2 * o2 + o3 * o3;
      u16x4 ph, pl;
      float oo[4] = {o0, o1, o2, o3};
      #pragma unroll
      for (int j = 0; j < 4; ++j) {
        u16 hv = f2bf(oo[j]);
        ph[j] = hv;
        pl[j] = f2bf(oo[j] - bf2f(hv));
      }
      const size_t off = ((size_t)b * 384 + (c - 384)) * NPIX + n0;
      *(u16x4*)(khi + off) = ph;
      *(u16x4*)(klo + off) = pl;
    }
  }
  if (isk) {
    __shared__ float sred[4][8];
    #pragma unroll
    for (int s = 0; s < 8; ++s) {
      float v = ssl[s];
      #pragma unroll
      for (int off = 32; off; off >>= 1) v += __shfl_down(v, off);
      if (lane == 0) sred[wv][s] = v;
    }
    __syncthreads();
    if (tid < 8) {
      float t = sred[0][tid] + sred[1][tid] + sred[2][tid] + sred[3][tid];
      atomicAdd(&ssqk[(size_t)b * DIM + (c0 - 384) + tid], t);
    }
  }
}

// ---- depthwise 3x3 on v pre + TRANSPOSED bf16 out [b][n][384] ----
__global__ __launch_bounds__(512, 4)
void k_dw3vT(const u16* __restrict__ src, const float* __restrict__ w9,
             const float* __restrict__ bias, u16* __restrict__ vT)
{
  __shared__ u16 th[256 * 64];   // 32 KB
  const int tid = threadIdx.x, wv = tid >> 6, lane = tid & 63;
  const int whw = blockIdx.x + 64 * (blockIdx.y + 6 * blockIdx.z);
  const int g = (whw & 7) + 8 * (whw >> 9);
  const int xchunk = (whw >> 3) & 63;
  const int cg = g % 6, b = g / 6;
  const int npx0 = xchunk * 256;
  const int n0 = npx0 + lane * 4;
  const int h = n0 >> 7, x0 = n0 & 127;
  const int c0 = cg * 64 + wv * 8;
  const int hm = (h > 0) ? h - 1 : 0, hp = (h < 127) ? h + 1 : 127;
  const float topf = (h > 0) ? 1.f : 0.f, botf = (h < 127) ? 1.f : 0.f;
  const u16* base = src + ((size_t)b * 384 + c0) * NPIX;
  u16x8 vh[4];
  #pragma unroll
  for (int s = 0; s < 8; ++s) {
    const int c = c0 + s;
    const u16* sp = base + (size_t)s * NPIX;
    const float* wc = w9 + c * 9;
    const float bz = bias[c];
    float o0 = bz, o1 = bz, o2 = bz, o3 = bz;
    row_acc_bf16(sp + hm * 128, x0, wc[0] * topf, wc[1] * topf, wc[2] * topf, o0, o1, o2, o3);
    row_acc_bf16(sp + h  * 128, x0, wc[3], wc[4], wc[5], o0, o1, o2, o3);
    row_acc_bf16(sp + hp * 128, x0, wc[6] * botf, wc[7] * botf, wc[8] * botf, o0, o1, o2, o3);
    vh[0][s] = f2bf(o0); vh[1][s] = f2bf(o1);
    vh[2][s] = f2bf(o2); vh[3][s] = f2bf(o3);
  }
  const int sl = (wv ^ (lane & 7)) * 8;
  #pragma unroll
  for (int j = 0; j < 4; ++j) {
    const int px = lane * 4 + j;
    *(u16x8*)&th[px * 64 + sl] = vh[j];
  }
  __syncthreads();
  if (tid < 256) {
    const int px = tid;
    u16* dst = vT + ((size_t)b * NPIX + npx0 + px) * 384 + cg * 64;
    const int rsw = (px >> 2) & 7;
    #pragma unroll
    for (int s = 0; s < 8; ++s)
      *(u16x8*)(dst + s * 8) = *(const u16x8*)&th[px * 64 + ((s ^ rsw) * 8)];
  }
}

// ---- depthwise 3x3 on [q(fp32), feature(fp32)] + exact GELU ----
__global__ __launch_bounds__(512, 4)
void k_qdw2(const float* __restrict__ qdwbuf, const float* __restrict__ feat,
            const float* __restrict__ w9, const float* __restrict__ bias,
            u16* __restrict__ qfhi, u16* __restrict__ qflo)
{
  __shared__ u16 th[256 * 64];   // 32 KB
  __shared__ u16 tl[256 * 64];   // 32 KB
  const int tid = threadIdx.x, wv = tid >> 6, lane = tid & 63;
  const int whw = blockIdx.x + 64 * (blockIdx.y + 12 * blockIdx.z);
  const int g = (whw & 7) + 8 * (whw >> 9);
  const int xchunk = (whw >> 3) & 63;
  const int cg = g % 12, b = g / 12;
  const int npx0 = xchunk * 256;
  const int n0 = npx0 + lane * 4;
  const int h = n0 >> 7, x0 = n0 & 127;
  const int c0 = cg * 64 + wv * 8;
  const int hm = (h > 0) ? h - 1 : 0, hp = (h < 127) ? h + 1 : 127;
  const float topf = (h > 0) ? 1.f : 0.f, botf = (h < 127) ? 1.f : 0.f;
  const bool isq = (c0 < 384);
  const float* base = isq ? (qdwbuf + ((size_t)b * 384 + c0) * NPIX)
                          : (feat   + ((size_t)b * 384 + (c0 - 384)) * NPIX);
  u16x8 vh[4], vl[4];
  #pragma unroll
  for (int s = 0; s < 8; ++s) {
    const int c = c0 + s;
    const float* sp = base + (size_t)s * NPIX;
    const float* wc = w9 + c * 9;
    const float bz = bias[c];
    float o0 = bz, o1 = bz, o2 = bz, o3 = bz;
    row_acc_f32(sp + hm * 128, x0, wc[0] * topf, wc[1] * topf, wc[2] * topf, o0, o1, o2, o3);
    row_acc_f32(sp + h  * 128, x0, wc[3], wc[4], wc[5], o0, o1, o2, o3);
    row_acc_f32(sp + hp * 128, x0, wc[6] * botf, wc[7] * botf, wc[8] * botf, o0, o1, o2, o3);
    float oo[4] = {o0, o1, o2, o3};
    #pragma unroll
    for (int j = 0; j < 4; ++j) {
      const float a = oo[j];
      const float g2 = 0.5f * a * (1.0f + erff(a * 0.70710678118654752440f));
      const u16 hv = f2bf(g2);
      vh[j][s] = hv;
      vl[j][s] = f2bf(g2 - bf2f(hv));
    }
  }
  const int sl = (wv ^ (lane & 7)) * 8;
  #pragma unroll
  for (int j = 0; j < 4; ++j) {
    const int px = lane * 4 + j;
    *(u16x8*)&th[px * 64 + sl] = vh[j];
    *(u16x8*)&tl[px * 64 + sl] = vl[j];
  }
  __syncthreads();
  const int sel = tid >> 8;
  const int px = tid & 255;
  const u16* srcb = sel ? tl : th;
  u16* dst = (sel ? qflo : qfhi) +
             ((size_t)b * NPIX + npx0 + px) * 768 + cg * 64;
  const int rsw = (px >> 2) & 7;
  #pragma unroll
  for (int s = 0; s < 8; ++s)
    *(u16x8*)(dst + s * 8) = *(const u16x8*)&srcb[px * 64 + ((s ^ rsw) * 8)];
}

// ---- QK^T 3-term: 2 chunks/block, 64 wave partials per bh ----
__global__ __launch_bounds__(256)
void k_qk3(const u16* __restrict__ qhi, const u16* __restrict__ qlo,
           const u16* __restrict__ khi, const u16* __restrict__ klo,
           float* __restrict__ part)
{
  const int wid = threadIdx.x >> 6, lane = threadIdx.x & 63;
  const int bh = blockIdx.y;
  const int b = bh >> 3, hd = bh & 7;
  const size_t base = ((size_t)b * 384 + hd * 48) * NPIX;
  const int cl = lane & 15, rl = lane >> 4;
  f32x4 acc[3][3];
  const f32x4 fz = {0.f, 0.f, 0.f, 0.f};
  #pragma unroll
  for (int i = 0; i < 3; ++i)
    #pragma unroll
    for (int j = 0; j < 3; ++j) acc[i][j] = fz;
  for (int ck = 0; ck < 2; ++ck) {
    const int n0 = (blockIdx.x * 2 + ck) * 512 + wid * 128;
    #pragma unroll
    for (int ks = 0; ks < 4; ++ks) {
      const int nn = n0 + ks * 32 + rl * 8;
      bf16x8 ah[3], al[3], bh16[3], bl16[3];
      #pragma unroll
      for (int i = 0; i < 3; ++i) {
        const size_t ro = base + (size_t)(i * 16 + cl) * NPIX + nn;
        ah[i]   = *(const bf16x8*)&qhi[ro];
        al[i]   = *(const bf16x8*)&qlo[ro];
        bh16[i] = *(const bf16x8*)&khi[ro];
        bl16[i] = *(const bf16x8*)&klo[ro];
      }
      #pragma unroll
      for (int i = 0; i < 3; ++i)
        #pragma unroll
        for (int j = 0; j < 3; ++j) {
          acc[i][j] = __builtin_amdgcn_mfma_f32_16x16x32_bf16(ah[i], bh16[j], acc[i][j], 0, 0, 0);
          acc[i][j] = __builtin_amdgcn_mfma_f32_16x16x32_bf16(ah[i], bl16[j], acc[i][j], 0, 0, 0);
          acc[i][j] = __builtin_amdgcn_mfma_f32_16x16x32_bf16(al[i], bh16[j], acc[i][j], 0, 0, 0);
        }
    }
  }
  float* pp = part + ((size_t)bh * 64 + blockIdx.x * 4 + wid) * 2304;
  #pragma unroll
  for (int i = 0; i < 3; ++i)
    #pragma unroll
    for (int j = 0; j < 3; ++j)
      #pragma unroll
      for (int r = 0; r < 4; ++r)
        pp[(i * 16 + rl * 4 + r) * 48 + (j * 16 + cl)] = acc[i][j][r];
}

// ---- reduce 64 partials -> raw[bh][48][48]  (288 blocks: TLP-bound) ----
__global__ void k_qkred(const float* __restrict__ part, float* __restrict__ raw)
{
  const int bh = blockIdx.x;
  const int p = blockIdx.y * 256 + threadIdx.x;   // < 2304
  const float* pp = part + (size_t)bh * 64 * 2304 + p;
  float s = 0.f;
  #pragma unroll 8
  for (int w = 0; w < 64; ++w) s += pp[(size_t)w * 2304];
  raw[(size_t)bh * 2304 + p] = s;
}

// ---- fused topk+softmax+Wa, WAVE-PARALLEL topk ----
__global__ void k_attn2(const float* __restrict__ raw, const float* __restrict__ ssq_q,
                        const float* __restrict__ ssq_k, const float* __restrict__ temp,
                        const int* __restrict__ Kp, const float* __restrict__ W,
                        u16* __restrict__ WaHi)
{
  __shared__ float at[48 * 49];
  const int bh = blockIdx.x, b = bh >> 3, hd = bh & 7;
  const int tid = threadIdx.x, wv = tid >> 6, lane = tid & 63;
  const int K = *Kp;
  const int d = lane;
  const bool act = (d < 48);
  const float ki = act ? 1.0f / fmaxf(sqrtf(ssq_k[b * DIM + hd * 48 + d]), 1e-12f) : 0.f;
  const float tmp = temp[hd];
  for (int r = 0; r < 12; ++r) {
    const int c = wv * 12 + r;
    const float qi = tmp / fmaxf(sqrtf(ssq_q[b * DIM + hd * 48 + c]), 1e-12f);
    const float v = act ? raw[(size_t)bh * 2304 + c * 48 + d] * qi * ki : -3.0e38f;
    int rank = 0;
    #pragma unroll
    for (int e = 0; e < 48; ++e) {
      const float ve = __shfl(v, e);
      rank += (ve > v || (ve == v && e < d)) ? 1 : 0;
    }
    const bool keep = act && (rank < K);
    float mx = keep ? v : -3.0e38f;
    #pragma unroll
    for (int off = 32; off; off >>= 1) mx = fmaxf(mx, __shfl_xor(mx, off));
    const float ex = keep ? expf(v - mx) : 0.f;
    float sum = ex;
    #pragma unroll
    for (int off = 32; off; off >>= 1) sum += __shfl_xor(sum, off);
    const float rs = 1.0f / sum;
    if (act) at[c * 49 + d] = ex * rs;
  }
  __syncthreads();
  for (int idx = tid; idx < 384 * 48; idx += 256) {
    const int m = idx / 48, dd = idx - m * 48;
    const float* wr = W + (size_t)m * 384 + hd * 48;
    float s = 0.f;
    #pragma unroll
    for (int c = 0; c < 48; ++c) s += wr[c] * at[c * 49 + dd];
    WaHi[((size_t)b * 384 + m) * 384 + hd * 48 + dd] = f2bf(s);
  }
}

extern "C" void kernel_launch(void* const* d_in, const int* in_sizes, int n_in,
                              void* d_out, int out_size, void* d_ws, size_t ws_size,
                              hipStream_t stream)
{
  (void)in_sizes; (void)n_in; (void)out_size; (void)ws_size;
  const float* x      = (const float*)d_in[0];
  const float* feat   = (const float*)d_in[1];
  const float* qkv_w  = (const float*)d_in[2];
  const float* qkv_b  = (const float*)d_in[3];
  const float* dw_w   = (const float*)d_in[4];
  const float* dw_b   = (const float*)d_in[5];
  const float* qdw_w  = (const float*)d_in[6];
  const float* qdw_b  = (const float*)d_in[7];
  const float* qpw_w  = (const float*)d_in[8];
  const float* qpw_b  = (const float*)d_in[9];
  const float* proj_w = (const float*)d_in[10];
  const float* proj_b = (const float*)d_in[11];
  const float* temp   = (const float*)d_in[12];
  const int*   Kp     = (const int*)d_in[13];

  char* ws = (char*)d_ws;
  const size_t HALF = 50331648;   // 48 MiB = NB*NPIX*DIM*2 bytes

  // R0 [0,16Mi): weights + attention small buffers
  u16* WqkvHi = (u16*)ws;                          // 1152*384
  u16* WqkvLo = WqkvHi + 1152 * 384;
  u16* WqpwHi = WqkvLo + 1152 * 384;               // 384*768
  u16* WqpwLo = WqpwHi + 384 * 768;
  float* ssqQ = (float*)(ws + 3244032);            // NB*DIM
  float* ssqK = ssqQ + NB * DIM;                   // NB*DIM
  float* raw  = ssqK + NB * DIM;                   // 32*2304 f32
  u16* WaHi   = (u16*)(ws + (4ull << 20));         // NB*384*384
  // R1 [16Mi, 112Mi): xThi/xTlo -> q_dw fp32 -> qhi/qlo
  char* R1 = ws + (16ull << 20);
  u16* xThi = (u16*)R1;
  u16* xTlo = (u16*)(R1 + HALF);
  float* qdwbuf = (float*)R1;                      // 96 MiB
  u16* qHi = (u16*)R1;
  u16* qLo = (u16*)(R1 + HALF);
  // R2 [112Mi, 304Mi): qk_pre fp32 -> qfT hi/lo -> (part 18.9MB -> vT)
  char* R2 = ws + (112ull << 20);
  float* qkpre = (float*)R2;                       // 192 MiB
  u16* qfHi = (u16*)R2;
  u16* qfLo = (u16*)(R2 + 2 * HALF);
  float* part = (float*)R2;                        // 32*64*2304 f32 (18.9 MiB)
  u16* vT   = (u16*)R2;                            // after k_qkred, 48 MiB
  // R3 [304Mi, 352Mi): v_pre bf16
  u16* vpre = (u16*)(ws + (304ull << 20));
  // d_out: khi/klo until proj overwrites
  u16* kHi = (u16*)d_out;
  u16* kLo = kHi + (size_t)NB * DIM * NPIX;

  hipMemsetAsync(ssqQ, 0, 2 * NB * DIM * sizeof(float), stream);
  k_cvt2x<<<dim3(1728, 2), 256, 0, stream>>>(qkv_w, WqkvHi, WqkvLo, 1152 * 384,
                                             qpw_w, WqpwHi, WqpwLo, 384 * 768);
  k_splitx<<<dim3(512, 6, NB), 256, 0, stream>>>(x, xThi, xTlo);
  // qkv GEMM, q+k channels, packed 3-term, fp32 out
  k_gemmP<0, false><<<dim3(128, 6, NB), 256, 0, stream>>>(WqkvHi, WqkvLo, xThi, xTlo,
      (void*)qkpre, nullptr, qkv_b, nullptr, 768, NPIX, 384);
  // qkv GEMM, v channels, 1-term, bf16 out
  k_gemmS<1><<<dim3(128, 3, NB), 256, 0, stream>>>(WqkvHi + (size_t)768 * 384,
      xThi, (void*)vpre, qkv_b + 768, 384, NPIX, 384, 0);
  k_dw3qk<<<dim3(16, 96, NB), 256, 0, stream>>>(qkpre, dw_w, dw_b, qdwbuf, kHi, kLo, ssqK);
  k_qdw2<<<dim3(64, 12, NB), 512, 0, stream>>>(qdwbuf, feat, qdw_w, qdw_b, qfHi, qfLo);
  // qpw GEMM, packed 3-term, hi/lo out, fused q sum-of-squares
  k_gemmP<2, true><<<dim3(128, 3, NB), 256, 0, stream>>>(WqpwHi, WqpwLo, qfHi, qfLo,
      (void*)qHi, qLo, qpw_b, ssqQ, 384, NPIX, 768);
  k_qk3<<<dim3(16, 32), 256, 0, stream>>>(qHi, qLo, kHi, kLo, part);
  k_qkred<<<dim3(32, 9), 256, 0, stream>>>(part, raw);
  // fused topk/softmax + Wa = Wproj*attn (wave-parallel topk)
  k_attn2<<<dim3(32), 256, 0, stream>>>(raw, ssqQ, ssqK, temp, Kp, proj_w, WaHi);
  // v depthwise (transposed out) AFTER k_qkred so vT can reuse R2
  k_dw3vT<<<dim3(64, 6, NB), 512, 0, stream>>>(vpre, dw_w + 768 * 9, dw_b + 768, vT);
  // fused proj: out = (Wproj*attn) * V, per-batch A
  k_gemmS<0><<<dim3(128, 3, NB), 256, 0, stream>>>(WaHi, vT,
      d_out, proj_b, 384, NPIX, 384, (size_t)384 * 384);
}